// Round 15
// baseline (29.274 us; speedup 1.0000x reference)
//
#include <hip/hip_runtime.h>
#include <math.h>

#define NLEAVES 8192
constexpr int NT = 1024;            // 16 waves -> 4 waves/SIMD (latency hiding)

typedef __fp16   h16x2 __attribute__((ext_vector_type(2)));   // cvt_pkrtz native
typedef _Float16 f16x2 __attribute__((ext_vector_type(2)));
typedef _Float16 f16x8 __attribute__((ext_vector_type(8)));
typedef float    f32x4 __attribute__((ext_vector_type(4)));

// ---- LDS layout (u32/f32 units) ----
// AF: E in MFMA A-frag layout: AF[(t*32+s)*64 + lane] = uint4 of 8 f16 =
//     E[lp = 16t + (lane&15)][l = s][r = (lane>>4)*8 .. +8]
// PF: P in B-frag layout: PF[s*64 + lane] = P[k=32s+(lane>>4)*8..+8][n=lane&15]
// PART: per-wave partial C tiles (16 x 256 f32, lane-major)
// AR: a-rows as dup f16 pairs, slot-stride 33 u32 (bank-spread)
// BB: b-rows as f16, slot-stride 80 B (16B-aligned, bank-spread)
constexpr int OFF_AF   = 0;                     // 16384 u32 (64 KB)
constexpr int OFF_PF   = 16384;                 // 8192 u32 (32 KB)
constexpr int OFF_PART = 24576;                 // 16*256 = 4096 f32
constexpr int OFF_AROW = 28672;                 // 32*33 u32
constexpr int OFF_BROW = 29728;                 // 32*20 u32 (80 B/slot)
constexpr int OFF_RM   = 30368;                 // 64 f32
constexpr int OFF_FLAG = 30432;
constexpr int SMEM_F32 = 30436;
constexpr size_t SMEM_BYTES = (size_t)SMEM_F32 * 4;   // ~119 KB -> 1 block/CU

__device__ __forceinline__ unsigned pkh(float a, float b) {
    h16x2 h = __builtin_amdgcn_cvt_pkrtz(a, b);
    return __builtin_bit_cast(unsigned, h);
}
__device__ __forceinline__ unsigned pkmul(unsigned a, unsigned b) {
    f16x2 x = __builtin_bit_cast(f16x2, a);
    f16x2 y = __builtin_bit_cast(f16x2, b);
    f16x2 r = x * y;                            // v_pk_mul_f16
    return __builtin_bit_cast(unsigned, r);
}

// Build exp(T) in f16 directly into A-fragment layout. Global reads coalesced;
// LDS writes contiguous 1 KB per wave (conflict-free).
__device__ __forceinline__ void build_AF(const float* __restrict__ trans,
                                         float* sm, int tid) {
    const float4* t4 = (const float4*)trans;    // t4[lp*256 + chunk*2 (+1)]
    uint4* AF = (uint4*)(sm + OFF_AF);
    const int lpl = tid & 15, hi = tid >> 4;    // hi 0..63
    #pragma unroll
    for (int j = 0; j < 4; ++j) {
        const int lp    = lpl + 16 * (j & 1);
        const int chunk = (hi & 31) + 32 * ((hi >> 5) + 2 * (j >> 1));  // 0..127
        float4 va = t4[lp * 256 + chunk * 2];
        float4 vb = t4[lp * 256 + chunk * 2 + 1];
        uint4 u;
        u.x = pkh(__expf(va.x), __expf(va.y));
        u.y = pkh(__expf(va.z), __expf(va.w));
        u.z = pkh(__expf(vb.x), __expf(vb.y));
        u.w = pkh(__expf(vb.z), __expf(vb.w));
        AF[((j & 1) * 32 + (chunk >> 2)) * 64 + (((chunk & 3) << 4) | lpl)] = u;
    }
}

__device__ __forceinline__ void load_AF(const float* __restrict__ wsE,
                                        float* sm, int tid) {
    const uint4* src = (const uint4*)wsE;
    uint4* AF = (uint4*)(sm + OFF_AF);
    #pragma unroll
    for (int it = 0; it < 4; ++it)
        AF[tid + it * NT] = src[tid + it * NT];
}

// Reduce IN rows through LEVELS tree levels. Per level: build P (outer
// products, f16), GEMM OUT = E x P on MFMA (16 waves = 2 M-tiles x 8 K-splits,
// K=1024), reduce partials + emissions + log in the epilogue.
// Row slot permutation slot(r) = (r&1)*16 + (r>>1): children (2n,2n+1) land at
// slots (n, 16+n) -> conflict-free access in P-build.
// All per-level iem rows are prefetched into registers at entry (emv[]),
// removing the serial L2/HBM load latency from each level's epilogue.
template<int IN, int LEVELS>
__device__ __forceinline__
void subtree(const float* __restrict__ in, float* __restrict__ outp,
             const float* __restrict__ iem, int NTOT, int blk,
             float* sm, int tid) {
    const int lp = tid & 31, q = tid >> 5;      // q 0..31
    uint4* AF = (uint4*)(sm + OFF_AF);
    uint4* PF = (uint4*)(sm + OFF_PF);
    float* PART = sm + OFF_PART;
    unsigned* AR = (unsigned*)(sm + OFF_AROW);
    char* BB = (char*)(sm + OFF_BROW);
    float* RM = sm + OFF_RM;

    // ---- prefetch emissions for every level (compile-time indexed regs) ----
    float emv[LEVELS];
    #pragma unroll
    for (int k = 1; k <= LEVELS; ++k) {
        const int m = IN >> k;
        if (q < m)
            emv[k - 1] = iem[(NLEAVES - 2 * (NTOT >> k) + blk * m + q) * 32 + lp];
    }

    // ---- prepass: rows -> exp(v - rowmax) in f16 (a: dup pairs, b: scalar) ----
    for (int rr = q; rr < IN; rr += 32) {
        float v = in[(blk * IN + rr) * 32 + lp];
        float gm = v;
        #pragma unroll
        for (int kk = 16; kk >= 1; kk >>= 1) gm = fmaxf(gm, __shfl_xor(gm, kk));
        const float e = __expf(v - gm);
        const int slot = (rr & 1) * 16 + (rr >> 1);
        AR[slot * 33 + lp] = pkh(e, e);
        *(_Float16*)(BB + slot * 80 + lp * 2) = (_Float16)e;
        if (lp == 0) RM[rr] = gm;
    }
    __syncthreads();

    #pragma unroll
    for (int k = 1; k <= LEVELS; ++k) {
        const int m = IN >> k;
        const float* rprev = RM + ((k & 1) ? 0 : 32);
        float*       rnext = RM + ((k & 1) ? 32 : 0);

        // ---- P build: P[:,n] = a_{2n} (x) b_{2n+1}, f16, B-frag layout ----
        {
            const int n = tid & 15, ocg = tid >> 4;       // ocg 0..63
            #pragma unroll
            for (int j = 0; j < 2; ++j) {
                const int og = ocg + 64 * j;              // k-octet 0..127
                const int l = og >> 2, roct = og & 3;
                const unsigned aa = AR[n * 33 + l];       // slot(2n)=n (broadcast)
                const uint4 bv = *(const uint4*)(BB + (16 + n) * 80 + roct * 16);
                uint4 p;
                p.x = pkmul(aa, bv.x); p.y = pkmul(aa, bv.y);
                p.z = pkmul(aa, bv.z); p.w = pkmul(aa, bv.w);
                PF[l * 64 + ((roct << 4) | n)] = p;       // lane-linear write
            }
        }
        __syncthreads();

        // ---- MFMA: wave w = (t = w&1 M-tile) x (kq = w>>1 K-eighth) ----
        {
            const int w = tid >> 6, lane = tid & 63;
            const int t = w & 1, kq = w >> 1;             // kq 0..7
            f32x4 acc = {0.f, 0.f, 0.f, 0.f};
            #pragma unroll
            for (int s4 = 0; s4 < 4; ++s4) {
                const int s = kq * 4 + s4;
                f16x8 af = __builtin_bit_cast(f16x8, AF[(t * 32 + s) * 64 + lane]);
                f16x8 bf = __builtin_bit_cast(f16x8, PF[s * 64 + lane]);
                acc = __builtin_amdgcn_mfma_f32_16x16x32_f16(af, bf, acc, 0, 0, 0);
            }
            *(f32x4*)(PART + w * 256 + lane * 4) = acc;   // lane-linear
        }
        __syncthreads();

        // ---- epilogue: reduce 8 K-partials, + em + rmaxes + log ----
        {
            const int n = q;                              // 0..31
            if (n < m) {
                const int t = lp >> 4, row = lp & 15;
                const int lane2 = ((row >> 2) << 4) | n, reg = row & 3;
                float sum = 0.f;
                #pragma unroll
                for (int kq = 0; kq < 8; ++kq)
                    sum += PART[(kq * 2 + t) * 256 + lane2 * 4 + reg];
                const float raw = emv[k - 1] + rprev[2 * n] + rprev[2 * n + 1] + __logf(sum);
                if (k == LEVELS) {
                    outp[blk * 32 + lp] = raw;            // m==1, n==0
                } else {
                    float gm = raw;
                    #pragma unroll
                    for (int kk = 16; kk >= 1; kk >>= 1) gm = fmaxf(gm, __shfl_xor(gm, kk));
                    const float e = __expf(raw - gm);
                    const int slot = (n & 1) * 16 + (n >> 1);
                    AR[slot * 33 + lp] = pkh(e, e);
                    *(_Float16*)(BB + slot * 80 + lp * 2) = (_Float16)e;
                    if (lp == 0) rnext[n] = gm;
                }
            }
        }
        __syncthreads();
    }
}

// K1: 256 blocks, 32 leaves each -> s1[256 rows]. Block 0 spills the finished
// f16 A-fragment table (64 KB) to wsE so the tail skips the expf rebuild.
// Kernel boundary = the system-level flush for s1/wsE (R6/R7: intra-kernel
// 256-block handoff is racy; R9: grid.sync costs ~37us each).
__global__ __launch_bounds__(NT, 1)
void k1_kernel(const float* __restrict__ leaf, float* __restrict__ s1,
               const float* __restrict__ iem, const float* __restrict__ trans,
               float* __restrict__ wsE) {
    extern __shared__ __align__(16) float sm[];
    const int tid = threadIdx.x;
    build_AF(trans, sm, tid);
    __syncthreads();                              // AF complete
    if (blockIdx.x == 0) {
        const uint4* src = (const uint4*)(sm + OFF_AF);
        uint4* dst = (uint4*)wsE;
        #pragma unroll
        for (int it = 0; it < 4; ++it)
            dst[tid + it * NT] = src[tid + it * NT];
    }
    subtree<32, 5>(leaf, s1, iem, 8192, blockIdx.x, sm, tid);
}

// Tail: 16 blocks reduce s1(256 rows) -> s2(16 rows); the last arriver reduces
// s2(16) -> out. Persistent counter, never reset: among any 16 consecutive
// fetch_add returns exactly one satisfies (old&15)==15 (wrap-safe from the
// 0xAA poison) -> no memset node. Fence pattern is R5/R8/R11's verbatim.
__global__ __launch_bounds__(NT, 1)
void tail_kernel(const float* __restrict__ s1, float* __restrict__ s2,
                 float* __restrict__ out, const float* __restrict__ iem,
                 const float* __restrict__ wsE, unsigned* __restrict__ cnt) {
    extern __shared__ __align__(16) float sm[];
    const int tid = threadIdx.x;
    int* flag = (int*)(sm + OFF_FLAG);
    load_AF(wsE, sm, tid);
    subtree<16, 4>(s1, s2, iem, 256, blockIdx.x, sm, tid);

    if (tid == 0) {
        __threadfence();                          // release s2 row device-wide
        unsigned old = atomicAdd(cnt, 1u);
        *flag = ((old & 15u) == 15u) ? 1 : 0;
    }
    __syncthreads();
    if (!*flag) return;
    if (tid == 0) __threadfence();                // acquire
    __syncthreads();

    subtree<16, 4>(s2, out, iem, 16, 0, sm, tid);
}

extern "C" void kernel_launch(void* const* d_in, const int* in_sizes, int n_in,
                              void* d_out, int out_size, void* d_ws, size_t ws_size,
                              hipStream_t stream) {
    const float* leaf  = (const float*)d_in[0];   // [8192,32]
    const float* iem   = (const float*)d_in[1];   // [8191,32]
    const float* trans = (const float*)d_in[2];   // [32,32,32]
    float* out = (float*)d_out;                   // [32]

    float* s1     = (float*)d_ws;                 // 256*32 f32   [0, 8192)
    float* s2     = s1 + 256 * 32;                // 16*32 f32    [8192, 8704)
    unsigned* cnt = (unsigned*)(s2 + 16 * 32);    // 1 u32 @ 8704, never reset
    float* wsE    = (float*)d_ws + 8720;          // 16384 u32 (64 KB f16 AF)

    (void)hipFuncSetAttribute((const void*)k1_kernel,
                              hipFuncAttributeMaxDynamicSharedMemorySize,
                              (int)SMEM_BYTES);
    (void)hipFuncSetAttribute((const void*)tail_kernel,
                              hipFuncAttributeMaxDynamicSharedMemorySize,
                              (int)SMEM_BYTES);

    k1_kernel<<<256, NT, SMEM_BYTES, stream>>>(leaf, s1, iem, trans, wsE);
    tail_kernel<<<16, NT, SMEM_BYTES, stream>>>(s1, s2, out, iem, wsE, cnt);
}

// Round 16
// 28.781 us; speedup vs baseline: 1.0171x; 1.0171x over previous
//
#include <hip/hip_runtime.h>
#include <math.h>

#define NLEAVES 8192
constexpr int NT = 512;             // 8 waves (R15 proved 16 waves regresses)

typedef __fp16   h16x2 __attribute__((ext_vector_type(2)));   // cvt_pkrtz native
typedef _Float16 f16x2 __attribute__((ext_vector_type(2)));
typedef _Float16 f16x8 __attribute__((ext_vector_type(8)));
typedef float    f32x4 __attribute__((ext_vector_type(4)));

// ---- LDS layout (u32/f32 units) ----
// AF: E in MFMA A-frag layout: AF[(t*32+s)*64 + lane] = uint4 of 8 f16 =
//     E[lp = 16t + (lane&15)][l = s][r = (lane>>4)*8 .. +8]
// PF: P in B-frag layout: PF[s*64 + lane] = P[k=32s+(lane>>4)*8..+8][n=lane&15]
// PART: per-wave partial C tiles (8 x 256 f32, lane-major)
// AR: a-rows as dup f16 pairs, slot-stride 33 u32 (bank-spread)
// BB: b-rows as f16, slot-stride 80 B (16B-aligned, bank-spread)
constexpr int OFF_AF   = 0;                     // 16384 u32 (64 KB)
constexpr int OFF_PF   = 16384;                 // 8192 u32 (32 KB)
constexpr int OFF_PART = 24576;                 // 2048 f32
constexpr int OFF_AROW = 26624;                 // 32*33 u32
constexpr int OFF_BROW = 27680;                 // 32*20 u32 (80 B/slot)
constexpr int OFF_RM   = 28320;                 // 64 f32
constexpr int OFF_FLAG = 28384;
constexpr int SMEM_F32 = 28388;
constexpr size_t SMEM_BYTES = (size_t)SMEM_F32 * 4;   // ~111 KB -> 1 block/CU

__device__ __forceinline__ unsigned pkh(float a, float b) {
    h16x2 h = __builtin_amdgcn_cvt_pkrtz(a, b);
    return __builtin_bit_cast(unsigned, h);
}
__device__ __forceinline__ unsigned pkmul(unsigned a, unsigned b) {
    f16x2 x = __builtin_bit_cast(f16x2, a);
    f16x2 y = __builtin_bit_cast(f16x2, b);
    f16x2 r = x * y;                            // v_pk_mul_f16
    return __builtin_bit_cast(unsigned, r);
}

// Build exp(T) in f16 directly into A-fragment layout. Global reads coalesced
// (each 64B line consumed exactly by 2 lanes); LDS writes are lane-linear per
// wave (wave w, iter j writes exactly fragment block (t=j&1, s=w+8*(j>>1))).
__device__ __forceinline__ void build_AF(const float* __restrict__ trans,
                                         float* sm, int tid) {
    const float4* t4 = (const float4*)trans;    // t4[lp*256 + chunk*2 (+1)]
    uint4* AF = (uint4*)(sm + OFF_AF);
    const int lpl = tid & 15, hi = tid >> 4;    // hi = w*4 + og
    #pragma unroll
    for (int j = 0; j < 8; ++j) {
        const int lp    = lpl + 16 * (j & 1);
        const int chunk = hi + 32 * (j >> 1);   // = l*4 + oct, 0..127
        float4 va = t4[lp * 256 + chunk * 2];
        float4 vb = t4[lp * 256 + chunk * 2 + 1];
        uint4 u;
        u.x = pkh(__expf(va.x), __expf(va.y));
        u.y = pkh(__expf(va.z), __expf(va.w));
        u.z = pkh(__expf(vb.x), __expf(vb.y));
        u.w = pkh(__expf(vb.z), __expf(vb.w));
        AF[((j & 1) * 32 + (chunk >> 2)) * 64 + (((chunk & 3) << 4) | lpl)] = u;
    }
}

__device__ __forceinline__ void load_AF(const float* __restrict__ wsE,
                                        float* sm, int tid) {
    const uint4* src = (const uint4*)wsE;
    uint4* AF = (uint4*)(sm + OFF_AF);
    #pragma unroll
    for (int it = 0; it < 8; ++it)
        AF[tid + it * NT] = src[tid + it * NT];
}

// Reduce IN rows through LEVELS tree levels. Per level: build P (outer
// products, f16), GEMM OUT = E x P on MFMA (8 waves = 2 M-tiles x 4 K-quarters,
// K=1024), reduce partials + emissions + log in the epilogue.
// Row slot permutation slot(r) = (r&1)*16 + (r>>1) makes children (2n, 2n+1)
// land at slots (n, 16+n) -> conflict-free consecutive access in P-build.
// All per-level iem rows are prefetched into registers at entry (emv[]): the
// loads issue back-to-back before the prepass, so no level's epilogue waits
// on L2/HBM latency.
template<int IN, int LEVELS>
__device__ __forceinline__
void subtree(const float* __restrict__ in, float* __restrict__ outp,
             const float* __restrict__ iem, int NTOT, int blk,
             float* sm, int tid) {
    const int lp = tid & 31, q = tid >> 5;      // q 0..15
    uint4* AF = (uint4*)(sm + OFF_AF);
    uint4* PF = (uint4*)(sm + OFF_PF);
    float* PART = sm + OFF_PART;
    unsigned* AR = (unsigned*)(sm + OFF_AROW);
    char* BB = (char*)(sm + OFF_BROW);
    float* RM = sm + OFF_RM;

    // ---- prefetch emissions for every level (compile-time indexed regs) ----
    float emv[LEVELS];
    #pragma unroll
    for (int k = 1; k <= LEVELS; ++k) {
        const int m = IN >> k;
        if (q < m)
            emv[k - 1] = iem[(NLEAVES - 2 * (NTOT >> k) + blk * m + q) * 32 + lp];
    }

    // ---- prepass: rows -> exp(v - rowmax) in f16 (a: dup pairs, b: scalar) ----
    for (int rr = q; rr < IN; rr += 16) {
        float v = in[(blk * IN + rr) * 32 + lp];
        float gm = v;
        #pragma unroll
        for (int kk = 16; kk >= 1; kk >>= 1) gm = fmaxf(gm, __shfl_xor(gm, kk));
        const float e = __expf(v - gm);
        const int slot = (rr & 1) * 16 + (rr >> 1);
        AR[slot * 33 + lp] = pkh(e, e);
        *(_Float16*)(BB + slot * 80 + lp * 2) = (_Float16)e;
        if (lp == 0) RM[rr] = gm;
    }
    __syncthreads();

    #pragma unroll
    for (int k = 1; k <= LEVELS; ++k) {
        const int m = IN >> k;
        const float* rprev = RM + ((k & 1) ? 0 : 32);
        float*       rnext = RM + ((k & 1) ? 32 : 0);

        // ---- P build: P[:,n] = a_{2n} (x) b_{2n+1}, f16, B-frag layout ----
        {
            const int n = tid & 15, ocg = tid >> 4;
            #pragma unroll
            for (int j = 0; j < 4; ++j) {
                const int og = ocg + 32 * j;          // k-octet 0..127
                const int l = og >> 2, roct = og & 3;
                const unsigned aa = AR[n * 33 + l];   // slot(2n) = n (broadcast)
                const uint4 bv = *(const uint4*)(BB + (16 + n) * 80 + roct * 16);
                uint4 p;
                p.x = pkmul(aa, bv.x); p.y = pkmul(aa, bv.y);
                p.z = pkmul(aa, bv.z); p.w = pkmul(aa, bv.w);
                PF[l * 64 + ((roct << 4) | n)] = p;   // lane-linear write
            }
        }
        __syncthreads();

        // ---- MFMA: wave w = (t = w&1 M-tile) x (kq = w>>1 K-quarter) ----
        {
            const int w = tid >> 6, lane = tid & 63;
            const int t = w & 1, kq = w >> 1;
            f32x4 acc = {0.f, 0.f, 0.f, 0.f};
            #pragma unroll
            for (int s8 = 0; s8 < 8; ++s8) {
                const int s = kq * 8 + s8;
                f16x8 af = __builtin_bit_cast(f16x8, AF[(t * 32 + s) * 64 + lane]);
                f16x8 bf = __builtin_bit_cast(f16x8, PF[s * 64 + lane]);
                acc = __builtin_amdgcn_mfma_f32_16x16x32_f16(af, bf, acc, 0, 0, 0);
            }
            *(f32x4*)(PART + w * 256 + lane * 4) = acc;   // lane-linear
        }
        __syncthreads();

        // ---- epilogue: reduce 4 K-partials, + em + rmaxes + log ----
        {
            const int n = tid >> 5;                   // 0..15
            if (n < m) {
                const int t = lp >> 4, row = lp & 15;
                const int lane2 = ((row >> 2) << 4) | n, reg = row & 3;
                float sum = 0.f;
                #pragma unroll
                for (int kq = 0; kq < 4; ++kq)
                    sum += PART[(kq * 2 + t) * 256 + lane2 * 4 + reg];
                const float raw = emv[k - 1] + rprev[2 * n] + rprev[2 * n + 1] + __logf(sum);
                if (k == LEVELS) {
                    outp[blk * 32 + lp] = raw;        // m==1, n==0
                } else {
                    float gm = raw;
                    #pragma unroll
                    for (int kk = 16; kk >= 1; kk >>= 1) gm = fmaxf(gm, __shfl_xor(gm, kk));
                    const float e = __expf(raw - gm);
                    const int slot = (n & 1) * 16 + (n >> 1);
                    AR[slot * 33 + lp] = pkh(e, e);
                    *(_Float16*)(BB + slot * 80 + lp * 2) = (_Float16)e;
                    if (lp == 0) rnext[n] = gm;
                }
            }
        }
        __syncthreads();
    }
}

// K1: 256 blocks, 32 leaves each -> s1[256 rows]. Block 0 spills the finished
// f16 A-fragment table (64 KB) to wsE so the tail skips the expf rebuild.
// Kernel boundary = the system-level flush for s1/wsE (R6/R7: intra-kernel
// 256-block handoff is racy; R9: grid.sync costs ~37us each).
__global__ __launch_bounds__(NT, 1)
void k1_kernel(const float* __restrict__ leaf, float* __restrict__ s1,
               const float* __restrict__ iem, const float* __restrict__ trans,
               float* __restrict__ wsE) {
    extern __shared__ __align__(16) float sm[];
    const int tid = threadIdx.x;
    build_AF(trans, sm, tid);
    __syncthreads();                              // AF complete
    if (blockIdx.x == 0) {
        const uint4* src = (const uint4*)(sm + OFF_AF);
        uint4* dst = (uint4*)wsE;
        #pragma unroll
        for (int it = 0; it < 8; ++it)
            dst[tid + it * NT] = src[tid + it * NT];
    }
    subtree<32, 5>(leaf, s1, iem, 8192, blockIdx.x, sm, tid);
}

// Tail: 16 blocks reduce s1(256 rows) -> s2(16 rows); the last arriver reduces
// s2(16) -> out. Persistent counter, never reset: among any 16 consecutive
// fetch_add returns exactly one satisfies (old&15)==15 (wrap-safe from the
// 0xAA poison) -> no memset node. Fence pattern is R5/R8/R11's verbatim.
__global__ __launch_bounds__(NT, 1)
void tail_kernel(const float* __restrict__ s1, float* __restrict__ s2,
                 float* __restrict__ out, const float* __restrict__ iem,
                 const float* __restrict__ wsE, unsigned* __restrict__ cnt) {
    extern __shared__ __align__(16) float sm[];
    const int tid = threadIdx.x;
    int* flag = (int*)(sm + OFF_FLAG);
    load_AF(wsE, sm, tid);
    subtree<16, 4>(s1, s2, iem, 256, blockIdx.x, sm, tid);

    if (tid == 0) {
        __threadfence();                          // release s2 row device-wide
        unsigned old = atomicAdd(cnt, 1u);
        *flag = ((old & 15u) == 15u) ? 1 : 0;
    }
    __syncthreads();
    if (!*flag) return;
    if (tid == 0) __threadfence();                // acquire
    __syncthreads();

    subtree<16, 4>(s2, out, iem, 16, 0, sm, tid);
}

extern "C" void kernel_launch(void* const* d_in, const int* in_sizes, int n_in,
                              void* d_out, int out_size, void* d_ws, size_t ws_size,
                              hipStream_t stream) {
    const float* leaf  = (const float*)d_in[0];   // [8192,32]
    const float* iem   = (const float*)d_in[1];   // [8191,32]
    const float* trans = (const float*)d_in[2];   // [32,32,32]
    float* out = (float*)d_out;                   // [32]

    float* s1     = (float*)d_ws;                 // 256*32 f32   [0, 8192)
    float* s2     = s1 + 256 * 32;                // 16*32 f32    [8192, 8704)
    unsigned* cnt = (unsigned*)(s2 + 16 * 32);    // 1 u32 @ 8704, never reset
    float* wsE    = (float*)d_ws + 8720;          // 16384 u32 (64 KB f16 AF)

    (void)hipFuncSetAttribute((const void*)k1_kernel,
                              hipFuncAttributeMaxDynamicSharedMemorySize,
                              (int)SMEM_BYTES);
    (void)hipFuncSetAttribute((const void*)tail_kernel,
                              hipFuncAttributeMaxDynamicSharedMemorySize,
                              (int)SMEM_BYTES);

    k1_kernel<<<256, NT, SMEM_BYTES, stream>>>(leaf, s1, iem, trans, wsE);
    tail_kernel<<<16, NT, SMEM_BYTES, stream>>>(s1, s2, out, iem, wsE, cnt);
}

// Round 17
// 28.076 us; speedup vs baseline: 1.0427x; 1.0251x over previous
//
#include <hip/hip_runtime.h>
#include <math.h>

#define NLEAVES 8192
constexpr int NT = 512;             // 8 waves (R15: 16 waves regresses; R16: prefetch neutral)

typedef __fp16   h16x2 __attribute__((ext_vector_type(2)));   // cvt_pkrtz native
typedef _Float16 f16x2 __attribute__((ext_vector_type(2)));
typedef _Float16 f16x8 __attribute__((ext_vector_type(8)));
typedef float    f32x4 __attribute__((ext_vector_type(4)));

// ---- LDS layout (u32/f32 units) ----
// AF: E in MFMA A-frag layout: AF[(t*32+s)*64 + lane] = uint4 of 8 f16 =
//     E[lp = 16t + (lane&15)][l = s][r = (lane>>4)*8 .. +8]
// PF: P in B-frag layout: PF[s*64 + lane] = P[k=32s+(lane>>4)*8..+8][n=lane&15]
// PART: per-wave partial C tiles (8 x 256 f32, lane-major)
// AR: a-rows as dup f16 pairs, slot-stride 33 u32 (bank-spread)
// BB: b-rows as f16, slot-stride 80 B (16B-aligned, bank-spread)
constexpr int OFF_AF   = 0;                     // 16384 u32 (64 KB)
constexpr int OFF_PF   = 16384;                 // 8192 u32 (32 KB)
constexpr int OFF_PART = 24576;                 // 2048 f32
constexpr int OFF_AROW = 26624;                 // 32*33 u32
constexpr int OFF_BROW = 27680;                 // 32*20 u32 (80 B/slot)
constexpr int OFF_RM   = 28320;                 // 64 f32
constexpr int OFF_FLAG = 28384;
constexpr int SMEM_F32 = 28388;
constexpr size_t SMEM_BYTES = (size_t)SMEM_F32 * 4;   // ~111 KB -> 1 block/CU

__device__ __forceinline__ unsigned pkh(float a, float b) {
    h16x2 h = __builtin_amdgcn_cvt_pkrtz(a, b);
    return __builtin_bit_cast(unsigned, h);
}
__device__ __forceinline__ unsigned pkmul(unsigned a, unsigned b) {
    f16x2 x = __builtin_bit_cast(f16x2, a);
    f16x2 y = __builtin_bit_cast(f16x2, b);
    f16x2 r = x * y;                            // v_pk_mul_f16
    return __builtin_bit_cast(unsigned, r);
}

// Build exp(T) in f16 directly into A-fragment layout. Global reads coalesced
// (each 64B line consumed exactly by 2 lanes); LDS writes are lane-linear per
// wave (wave w, iter j writes exactly fragment block (t=j&1, s=w+8*(j>>1))).
__device__ __forceinline__ void build_AF(const float* __restrict__ trans,
                                         float* sm, int tid) {
    const float4* t4 = (const float4*)trans;    // t4[lp*256 + chunk*2 (+1)]
    uint4* AF = (uint4*)(sm + OFF_AF);
    const int lpl = tid & 15, hi = tid >> 4;    // hi = w*4 + og
    #pragma unroll
    for (int j = 0; j < 8; ++j) {
        const int lp    = lpl + 16 * (j & 1);
        const int chunk = hi + 32 * (j >> 1);   // = l*4 + oct, 0..127
        float4 va = t4[lp * 256 + chunk * 2];
        float4 vb = t4[lp * 256 + chunk * 2 + 1];
        uint4 u;
        u.x = pkh(__expf(va.x), __expf(va.y));
        u.y = pkh(__expf(va.z), __expf(va.w));
        u.z = pkh(__expf(vb.x), __expf(vb.y));
        u.w = pkh(__expf(vb.z), __expf(vb.w));
        AF[((j & 1) * 32 + (chunk >> 2)) * 64 + (((chunk & 3) << 4) | lpl)] = u;
    }
}

__device__ __forceinline__ void load_AF(const float* __restrict__ wsE,
                                        float* sm, int tid) {
    const uint4* src = (const uint4*)wsE;
    uint4* AF = (uint4*)(sm + OFF_AF);
    #pragma unroll
    for (int it = 0; it < 8; ++it)
        AF[tid + it * NT] = src[tid + it * NT];
}

// Reduce IN rows through LEVELS tree levels. Per level: build P (outer
// products, f16), GEMM OUT = E x P on MFMA (8 waves = 2 M-tiles x 4 K-quarters,
// K=1024), reduce partials + emissions + log in the epilogue.
// Row slot permutation slot(r) = (r&1)*16 + (r>>1) makes children (2n, 2n+1)
// land at slots (n, 16+n) -> conflict-free consecutive access in P-build.
template<int IN, int LEVELS>
__device__ __forceinline__
void subtree(const float* __restrict__ in, float* __restrict__ outp,
             const float* __restrict__ iem, int NTOT, int blk,
             float* sm, int tid) {
    const int lp = tid & 31, q = tid >> 5;
    uint4* AF = (uint4*)(sm + OFF_AF);
    uint4* PF = (uint4*)(sm + OFF_PF);
    float* PART = sm + OFF_PART;
    unsigned* AR = (unsigned*)(sm + OFF_AROW);
    char* BB = (char*)(sm + OFF_BROW);
    float* RM = sm + OFF_RM;

    // ---- prepass: rows -> exp(v - rowmax) in f16 (a: dup pairs, b: scalar) ----
    for (int rr = q; rr < IN; rr += 16) {
        float v = in[(blk * IN + rr) * 32 + lp];
        float gm = v;
        #pragma unroll
        for (int kk = 16; kk >= 1; kk >>= 1) gm = fmaxf(gm, __shfl_xor(gm, kk));
        const float e = __expf(v - gm);
        const int slot = (rr & 1) * 16 + (rr >> 1);
        AR[slot * 33 + lp] = pkh(e, e);
        *(_Float16*)(BB + slot * 80 + lp * 2) = (_Float16)e;
        if (lp == 0) RM[rr] = gm;
    }
    __syncthreads();

    #pragma unroll
    for (int k = 1; k <= LEVELS; ++k) {
        const int m = IN >> k;
        const float* rprev = RM + ((k & 1) ? 0 : 32);
        float*       rnext = RM + ((k & 1) ? 32 : 0);

        // ---- P build: P[:,n] = a_{2n} (x) b_{2n+1}, f16, B-frag layout ----
        {
            const int n = tid & 15, ocg = tid >> 4;
            #pragma unroll
            for (int j = 0; j < 4; ++j) {
                const int og = ocg + 32 * j;          // k-octet 0..127
                const int l = og >> 2, roct = og & 3;
                const unsigned aa = AR[n * 33 + l];   // slot(2n) = n (broadcast)
                const uint4 bv = *(const uint4*)(BB + (16 + n) * 80 + roct * 16);
                uint4 p;
                p.x = pkmul(aa, bv.x); p.y = pkmul(aa, bv.y);
                p.z = pkmul(aa, bv.z); p.w = pkmul(aa, bv.w);
                PF[l * 64 + ((roct << 4) | n)] = p;   // lane-linear write
            }
        }
        __syncthreads();

        // ---- MFMA: wave w = (t = w&1 M-tile) x (kq = w>>1 K-quarter) ----
        {
            const int w = tid >> 6, lane = tid & 63;
            const int t = w & 1, kq = w >> 1;
            f32x4 acc = {0.f, 0.f, 0.f, 0.f};
            #pragma unroll
            for (int s8 = 0; s8 < 8; ++s8) {
                const int s = kq * 8 + s8;
                f16x8 af = __builtin_bit_cast(f16x8, AF[(t * 32 + s) * 64 + lane]);
                f16x8 bf = __builtin_bit_cast(f16x8, PF[s * 64 + lane]);
                acc = __builtin_amdgcn_mfma_f32_16x16x32_f16(af, bf, acc, 0, 0, 0);
            }
            *(f32x4*)(PART + w * 256 + lane * 4) = acc;   // lane-linear
        }
        __syncthreads();

        // ---- epilogue: reduce 4 K-partials, + em + rmaxes + log ----
        {
            const int n = tid >> 5;                   // 0..15
            if (n < m) {
                const int t = lp >> 4, row = lp & 15;
                const int lane2 = ((row >> 2) << 4) | n, reg = row & 3;
                float sum = 0.f;
                #pragma unroll
                for (int kq = 0; kq < 4; ++kq)
                    sum += PART[(kq * 2 + t) * 256 + lane2 * 4 + reg];
                const float em = iem[(NLEAVES - 2 * (NTOT >> k) + blk * m + n) * 32 + lp];
                const float raw = em + rprev[2 * n] + rprev[2 * n + 1] + __logf(sum);
                if (k == LEVELS) {
                    outp[blk * 32 + lp] = raw;        // m==1, n==0
                } else {
                    float gm = raw;
                    #pragma unroll
                    for (int kk = 16; kk >= 1; kk >>= 1) gm = fmaxf(gm, __shfl_xor(gm, kk));
                    const float e = __expf(raw - gm);
                    const int slot = (n & 1) * 16 + (n >> 1);
                    AR[slot * 33 + lp] = pkh(e, e);
                    *(_Float16*)(BB + slot * 80 + lp * 2) = (_Float16)e;
                    if (lp == 0) rnext[n] = gm;
                }
            }
        }
        __syncthreads();
    }
}

// K1: 256 blocks, 32 leaves each -> s1[256 rows]. Block 0 spills the finished
// f16 A-fragment table (64 KB) to wsE so the tail skips the expf rebuild.
// Kernel boundary = the system-level flush for s1/wsE (R6/R7: intra-kernel
// 256-block handoff is racy; R9: grid.sync costs ~37us each).
__global__ __launch_bounds__(NT, 1)
void k1_kernel(const float* __restrict__ leaf, float* __restrict__ s1,
               const float* __restrict__ iem, const float* __restrict__ trans,
               float* __restrict__ wsE) {
    extern __shared__ __align__(16) float sm[];
    const int tid = threadIdx.x;
    build_AF(trans, sm, tid);
    __syncthreads();                              // AF complete
    if (blockIdx.x == 0) {
        const uint4* src = (const uint4*)(sm + OFF_AF);
        uint4* dst = (uint4*)wsE;
        #pragma unroll
        for (int it = 0; it < 8; ++it)
            dst[tid + it * NT] = src[tid + it * NT];
    }
    subtree<32, 5>(leaf, s1, iem, 8192, blockIdx.x, sm, tid);
}

// Tail: 16 blocks reduce s1(256 rows) -> s2(16 rows); the last arriver reduces
// s2(16) -> out. Persistent counter, never reset: among any 16 consecutive
// fetch_add returns exactly one satisfies (old&15)==15 (wrap-safe from the
// 0xAA poison) -> no memset node. Fence pattern is R5/R8/R11's verbatim.
__global__ __launch_bounds__(NT, 1)
void tail_kernel(const float* __restrict__ s1, float* __restrict__ s2,
                 float* __restrict__ out, const float* __restrict__ iem,
                 const float* __restrict__ wsE, unsigned* __restrict__ cnt) {
    extern __shared__ __align__(16) float sm[];
    const int tid = threadIdx.x;
    int* flag = (int*)(sm + OFF_FLAG);
    load_AF(wsE, sm, tid);
    subtree<16, 4>(s1, s2, iem, 256, blockIdx.x, sm, tid);

    if (tid == 0) {
        __threadfence();                          // release s2 row device-wide
        unsigned old = atomicAdd(cnt, 1u);
        *flag = ((old & 15u) == 15u) ? 1 : 0;
    }
    __syncthreads();
    if (!*flag) return;
    if (tid == 0) __threadfence();                // acquire
    __syncthreads();

    subtree<16, 4>(s2, out, iem, 16, 0, sm, tid);
}

extern "C" void kernel_launch(void* const* d_in, const int* in_sizes, int n_in,
                              void* d_out, int out_size, void* d_ws, size_t ws_size,
                              hipStream_t stream) {
    const float* leaf  = (const float*)d_in[0];   // [8192,32]
    const float* iem   = (const float*)d_in[1];   // [8191,32]
    const float* trans = (const float*)d_in[2];   // [32,32,32]
    float* out = (float*)d_out;                   // [32]

    float* s1     = (float*)d_ws;                 // 256*32 f32   [0, 8192)
    float* s2     = s1 + 256 * 32;                // 16*32 f32    [8192, 8704)
    unsigned* cnt = (unsigned*)(s2 + 16 * 32);    // 1 u32 @ 8704, never reset
    float* wsE    = (float*)d_ws + 8720;          // 16384 u32 (64 KB f16 AF)

    (void)hipFuncSetAttribute((const void*)k1_kernel,
                              hipFuncAttributeMaxDynamicSharedMemorySize,
                              (int)SMEM_BYTES);
    (void)hipFuncSetAttribute((const void*)tail_kernel,
                              hipFuncAttributeMaxDynamicSharedMemorySize,
                              (int)SMEM_BYTES);

    k1_kernel<<<256, NT, SMEM_BYTES, stream>>>(leaf, s1, iem, trans, wsE);
    tail_kernel<<<16, NT, SMEM_BYTES, stream>>>(s1, s2, out, iem, wsE, cnt);
}